// Round 5
// baseline (53.412 us; speedup 1.0000x reference)
//
#include <hip/hip_runtime.h>
#include <hip/hip_bf16.h>

#define N_SIDE 14
#define N_PATCH (N_SIDE * N_SIDE)   // 196
#define D_BB 384
#define DQ_BB (D_BB / 4)             // 96 float4 per cell
#define D_MODEL 512
#define CQ (D_MODEL / 4)             // 128 col-quads
#define BT_TOTAL 2048
#define LN_EPS 1e-5f
#define ROWS 8                       // rows per gemm block
#define KP 4                         // K partitions per gemm block
#define KCHUNK (D_BB / KP)           // 96
#define GROUPS 4                     // cell groups per pool sub-block
#define SPLIT 2                      // sub-blocks per bt
#define ESTRIDE (GROUPS * SPLIT)     // 8 effective groups

__device__ __forceinline__ void fma4(float4& a, float s, const float4& wv) {
    a.x = fmaf(s, wv.x, a.x);
    a.y = fmaf(s, wv.y, a.y);
    a.z = fmaf(s, wv.z, a.z);
    a.w = fmaf(s, wv.w, a.w);
}

__device__ __forceinline__ void box_params(const float* __restrict__ bboxes, int bt,
                                           int& x1, int& y1, int& wd, int& total) {
    const float bx1 = bboxes[bt * 4 + 0];
    const float by1 = bboxes[bt * 4 + 1];
    const float bx2 = bboxes[bt * 4 + 2];
    const float by2 = bboxes[bt * 4 + 3];
    // match reference exactly: clip -> trunc/ceil -> clip -> max
    x1 = (int)fminf(fmaxf(bx1 * (float)N_SIDE, 0.f), (float)(N_SIDE - 1));
    y1 = (int)fminf(fmaxf(by1 * (float)N_SIDE, 0.f), (float)(N_SIDE - 1));
    int x2 = (int)fminf(fmaxf(ceilf(fminf(fmaxf(bx2 * (float)N_SIDE, 0.f), (float)N_SIDE)), 1.f), (float)N_SIDE);
    int y2 = (int)fminf(fmaxf(ceilf(fminf(fmaxf(by2 * (float)N_SIDE, 0.f), (float)N_SIDE)), 1.f), (float)N_SIDE);
    x2 = max(x2, x1 + 1);
    y2 = max(y2, y1 + 1);
    wd = x2 - x1;
    total = wd * (y2 - y1);
}

// ---------------- Kernel 1: ROI pool partial sums ----------------
// grid = BT_TOTAL*SPLIT, block = 384 = 96 quads x 4 cell-groups.
// Sub-block s handles interleaved cells; partials atomicAdd'ed into pooled sums.
__global__ __launch_bounds__(384) void pool_kernel(
    const float* __restrict__ patch,   // [BT,196,384]
    const float* __restrict__ bboxes,  // [BT,4]
    float* __restrict__ pooled)        // [BT,384] raw sums (pre-zeroed)
{
    const int bid = blockIdx.x;
    const int bt  = bid >> 1;
    const int s   = bid & 1;
    const int t   = threadIdx.x;
    const int qd  = t % DQ_BB;              // channel quad 0..95
    const int g   = t / DQ_BB;              // cell group 0..3
    const int e   = s * GROUPS + g;         // effective group 0..7

    int x1, y1, wd, total;
    box_params(bboxes, bt, x1, y1, wd, total);
    const float inv_wd = 1.f / (float)wd;
    const int cell0 = y1 * N_SIDE + x1;

    const float4* __restrict__ base = (const float4*)patch + (size_t)bt * N_PATCH * DQ_BB + qd;

    // flattened cell c -> grid offset (exact: (c+0.5)/wd is never near an integer)
    auto cell_off = [&](int c) -> size_t {
        const int y = (int)(((float)c + 0.5f) * inv_wd);
        const int x = c - y * wd;
        return (size_t)(cell0 + y * N_SIDE + x) * DQ_BB;
    };

    float4 acc = make_float4(0.f, 0.f, 0.f, 0.f);
    int c = e;
    // 4-deep: issue 4 independent loads, then accumulate
    for (; c + 3 * ESTRIDE < total; c += 4 * ESTRIDE) {
        const float4 v0 = base[cell_off(c)];
        const float4 v1 = base[cell_off(c + ESTRIDE)];
        const float4 v2 = base[cell_off(c + 2 * ESTRIDE)];
        const float4 v3 = base[cell_off(c + 3 * ESTRIDE)];
        acc.x += (v0.x + v1.x) + (v2.x + v3.x);
        acc.y += (v0.y + v1.y) + (v2.y + v3.y);
        acc.z += (v0.z + v1.z) + (v2.z + v3.z);
        acc.w += (v0.w + v1.w) + (v2.w + v3.w);
    }
    for (; c < total; c += ESTRIDE) {
        const float4 v = base[cell_off(c)];
        acc.x += v.x; acc.y += v.y; acc.z += v.z; acc.w += v.w;
    }

    __shared__ float4 part[GROUPS][DQ_BB];   // 6 KB
    part[g][qd] = acc;
    __syncthreads();

    if (t < DQ_BB) {
        float4 sm = part[0][t];
#pragma unroll
        for (int p = 1; p < GROUPS; ++p) {
            const float4 v = part[p][t];
            sm.x += v.x; sm.y += v.y; sm.z += v.z; sm.w += v.w;
        }
        float* dst = pooled + (size_t)bt * D_BB + t * 4;
        atomicAdd(dst + 0, sm.x);
        atomicAdd(dst + 1, sm.y);
        atomicAdd(dst + 2, sm.z);
        atomicAdd(dst + 3, sm.w);
    }
}

// ---------------- Kernel 2: GEMM (sums @ W)/count + b + LayerNorm + vis blend ----------------
// grid = BT_TOTAL/ROWS = 256, block = 512 = 128 col-quads x 4 K-partitions
__global__ __launch_bounds__(512) void gemm_ln_kernel(
    const float* __restrict__ pooled,    // [BT,384] raw sums
    const float* __restrict__ bboxes,    // [BT,4]
    const float* __restrict__ W,         // [384,512]
    const float* __restrict__ bias,      // [512]
    const float* __restrict__ gamma,     // [512]
    const float* __restrict__ beta,      // [512]
    const float* __restrict__ mask_tok,  // [512]
    const float* __restrict__ vis,       // [BT]
    float* __restrict__ out)             // [BT,512]
{
    const int tid  = threadIdx.x;
    const int part = tid >> 7;       // 0..3 (K partition)
    const int jq   = tid & 127;      // col quad 0..127
    const int r0   = blockIdx.x * ROWS;

    __shared__ float sp[ROWS][D_BB];            // 12 KB: the 8 pooled-sum rows
    __shared__ float red[KP - 1][32][CQ];       // 48 KB, element-major: conflict-free
    __shared__ float lnred[2][ROWS][2];
    __shared__ float s_invc[ROWS];

    // ---- stage pooled rows into LDS (vectorized, coalesced) ----
    {
        const float4* p4  = (const float4*)(pooled + (size_t)r0 * D_BB);
        float4*       sp4 = (float4*)sp;
        for (int i = tid; i < ROWS * DQ_BB; i += 512) sp4[i] = p4[i];
    }
    if (tid < ROWS) {
        int x1, y1, wd, total;
        box_params(bboxes, r0 + tid, x1, y1, wd, total);
        s_invc[tid] = 1.f / (float)total;
    }
    __syncthreads();

    const float4* Wq = (const float4*)W;   // [384][128] float4
    float4 acc[ROWS];
#pragma unroll
    for (int r = 0; r < ROWS; ++r) acc[r] = make_float4(0.f, 0.f, 0.f, 0.f);

    const int dbase = part * KCHUNK;
#pragma unroll 2
    for (int i = 0; i < KCHUNK / 4; ++i) {
        const int d = dbase + i * 4;
        const float4 w0 = Wq[(size_t)(d + 0) * CQ + jq];
        const float4 w1 = Wq[(size_t)(d + 1) * CQ + jq];
        const float4 w2 = Wq[(size_t)(d + 2) * CQ + jq];
        const float4 w3 = Wq[(size_t)(d + 3) * CQ + jq];
#pragma unroll
        for (int r = 0; r < ROWS; ++r) {
            const float4 a = *(const float4*)&sp[r][d];   // LDS broadcast
            fma4(acc[r], a.x, w0);
            fma4(acc[r], a.y, w1);
            fma4(acc[r], a.z, w2);
            fma4(acc[r], a.w, w3);
        }
    }

    // ---- cross-partition reduction via LDS ----
    if (part != 0) {
#pragma unroll
        for (int r = 0; r < ROWS; ++r) {
            red[part - 1][r * 4 + 0][jq] = acc[r].x;
            red[part - 1][r * 4 + 1][jq] = acc[r].y;
            red[part - 1][r * 4 + 2][jq] = acc[r].z;
            red[part - 1][r * 4 + 3][jq] = acc[r].w;
        }
    }
    __syncthreads();

    if (part == 0) {
#pragma unroll
        for (int p = 0; p < KP - 1; ++p) {
#pragma unroll
            for (int r = 0; r < ROWS; ++r) {
                acc[r].x += red[p][r * 4 + 0][jq];
                acc[r].y += red[p][r * 4 + 1][jq];
                acc[r].z += red[p][r * 4 + 2][jq];
                acc[r].w += red[p][r * 4 + 3][jq];
            }
        }
        const float4 bj = ((const float4*)bias)[jq];
#pragma unroll
        for (int r = 0; r < ROWS; ++r) {
            const float ic = s_invc[r];
            acc[r].x = fmaf(acc[r].x, ic, bj.x);
            acc[r].y = fmaf(acc[r].y, ic, bj.y);
            acc[r].z = fmaf(acc[r].z, ic, bj.z);
            acc[r].w = fmaf(acc[r].w, ic, bj.w);
        }

        // ---- LN partial sums across 128 threads (2 waves) ----
        const int lane = tid & 63;
        const int wv   = tid >> 6;   // 0 or 1
#pragma unroll
        for (int r = 0; r < ROWS; ++r) {
            float s  = acc[r].x + acc[r].y + acc[r].z + acc[r].w;
            float s2 = acc[r].x * acc[r].x + acc[r].y * acc[r].y +
                       acc[r].z * acc[r].z + acc[r].w * acc[r].w;
#pragma unroll
            for (int off = 32; off >= 1; off >>= 1) {
                s  += __shfl_xor(s,  off);
                s2 += __shfl_xor(s2, off);
            }
            if (lane == 0) { lnred[wv][r][0] = s; lnred[wv][r][1] = s2; }
        }
    }
    __syncthreads();

    if (part == 0) {
        const float4 g4 = ((const float4*)gamma)[jq];
        const float4 b4 = ((const float4*)beta)[jq];
        const float4 m4 = ((const float4*)mask_tok)[jq];
#pragma unroll
        for (int r = 0; r < ROWS; ++r) {
            const float s    = lnred[0][r][0] + lnred[1][r][0];
            const float s2   = lnred[0][r][1] + lnred[1][r][1];
            const float mean = s * (1.f / (float)D_MODEL);
            const float var  = s2 * (1.f / (float)D_MODEL) - mean * mean;
            const float rstd = rsqrtf(var + LN_EPS);
            const float v    = vis[r0 + r];
            const float iv   = 1.f - v;
            float4 o;
            o.x = v * ((acc[r].x - mean) * rstd * g4.x + b4.x) + iv * m4.x;
            o.y = v * ((acc[r].y - mean) * rstd * g4.y + b4.y) + iv * m4.y;
            o.z = v * ((acc[r].z - mean) * rstd * g4.z + b4.z) + iv * m4.z;
            o.w = v * ((acc[r].w - mean) * rstd * g4.w + b4.w) + iv * m4.w;
            ((float4*)out)[(size_t)(r0 + r) * CQ + jq] = o;
        }
    }
}

extern "C" void kernel_launch(void* const* d_in, const int* in_sizes, int n_in,
                              void* d_out, int out_size, void* d_ws, size_t ws_size,
                              hipStream_t stream) {
    const float* patch  = (const float*)d_in[0];  // [2048,196,384]
    const float* bboxes = (const float*)d_in[1];  // [2048,4]
    const float* vis    = (const float*)d_in[2];  // [2048]
    // d_in[3] = B, d_in[4] = T (scalars, unused)
    const float* W      = (const float*)d_in[5];  // [384,512]
    const float* bias   = (const float*)d_in[6];  // [512]
    const float* gamma  = (const float*)d_in[7];  // [512]
    const float* beta   = (const float*)d_in[8];  // [512]
    const float* mtok   = (const float*)d_in[9];  // [1,512]

    float* pooled = (float*)d_ws;                 // [2048,384] raw sums, 3 MB
    float* out    = (float*)d_out;

    hipMemsetAsync(pooled, 0, (size_t)BT_TOTAL * D_BB * sizeof(float), stream);
    pool_kernel<<<BT_TOTAL * SPLIT, 384, 0, stream>>>(patch, bboxes, pooled);
    gemm_ln_kernel<<<BT_TOTAL / ROWS, 512, 0, stream>>>(
        pooled, bboxes, W, bias, gamma, beta, mtok, vis, out);
}

// Round 6
// 38.550 us; speedup vs baseline: 1.3855x; 1.3855x over previous
//
#include <hip/hip_runtime.h>
#include <hip/hip_bf16.h>

#define N_SIDE 14
#define N_PATCH (N_SIDE * N_SIDE)   // 196
#define D_BB 384
#define DQ_BB (D_BB / 4)             // 96 float4 per cell
#define D_MODEL 512
#define CQ (D_MODEL / 4)             // 128 col-quads
#define BT_TOTAL 2048
#define LN_EPS 1e-5f
#define ROWS 8                       // rows per gemm block
#define KP 4                         // K partitions per gemm block
#define KCHUNK (D_BB / KP)           // 96
#define GROUPS 4                     // cell groups per pool sub-block
#define SPLIT 2                      // sub-blocks per bt (disjoint outputs)
#define ESTRIDE (GROUPS * SPLIT)     // 8 effective groups

__device__ __forceinline__ void fma4(float4& a, float s, const float4& wv) {
    a.x = fmaf(s, wv.x, a.x);
    a.y = fmaf(s, wv.y, a.y);
    a.z = fmaf(s, wv.z, a.z);
    a.w = fmaf(s, wv.w, a.w);
}

__device__ __forceinline__ void box_params(const float* __restrict__ bboxes, int bt,
                                           int& x1, int& y1, int& wd, int& total) {
    const float bx1 = bboxes[bt * 4 + 0];
    const float by1 = bboxes[bt * 4 + 1];
    const float bx2 = bboxes[bt * 4 + 2];
    const float by2 = bboxes[bt * 4 + 3];
    // match reference exactly: clip -> trunc/ceil -> clip -> max
    x1 = (int)fminf(fmaxf(bx1 * (float)N_SIDE, 0.f), (float)(N_SIDE - 1));
    y1 = (int)fminf(fmaxf(by1 * (float)N_SIDE, 0.f), (float)(N_SIDE - 1));
    int x2 = (int)fminf(fmaxf(ceilf(fminf(fmaxf(bx2 * (float)N_SIDE, 0.f), (float)N_SIDE)), 1.f), (float)N_SIDE);
    int y2 = (int)fminf(fmaxf(ceilf(fminf(fmaxf(by2 * (float)N_SIDE, 0.f), (float)N_SIDE)), 1.f), (float)N_SIDE);
    x2 = max(x2, x1 + 1);
    y2 = max(y2, y1 + 1);
    wd = x2 - x1;
    total = wd * (y2 - y1);
}

// ---------------- Kernel 1: ROI pool partial sums ----------------
// grid = BT_TOTAL*SPLIT, block = 384 = 96 quads x 4 cell-groups.
// Sub-block s sums its interleaved cells into its OWN buffer slice (no atomics).
__global__ __launch_bounds__(384) void pool_kernel(
    const float* __restrict__ patch,   // [BT,196,384]
    const float* __restrict__ bboxes,  // [BT,4]
    float* __restrict__ pooled)        // [SPLIT,BT,384] raw partial sums
{
    const int bid = blockIdx.x;
    const int bt  = bid >> 1;
    const int s   = bid & 1;
    const int t   = threadIdx.x;
    const int qd  = t % DQ_BB;              // channel quad 0..95
    const int g   = t / DQ_BB;              // cell group 0..3
    const int e   = s * GROUPS + g;         // effective group 0..7

    int x1, y1, wd, total;
    box_params(bboxes, bt, x1, y1, wd, total);
    const float inv_wd = 1.f / (float)wd;
    const int cell0 = y1 * N_SIDE + x1;

    const float4* __restrict__ base = (const float4*)patch + (size_t)bt * N_PATCH * DQ_BB + qd;

    // flattened cell c -> grid offset (exact: (c+0.5)/wd is never near an integer)
    auto cell_off = [&](int c) -> size_t {
        const int y = (int)(((float)c + 0.5f) * inv_wd);
        const int x = c - y * wd;
        return (size_t)(cell0 + y * N_SIDE + x) * DQ_BB;
    };

    float4 acc = make_float4(0.f, 0.f, 0.f, 0.f);
    int c = e;
    // 4-deep: issue 4 independent loads, then accumulate
    for (; c + 3 * ESTRIDE < total; c += 4 * ESTRIDE) {
        const float4 v0 = base[cell_off(c)];
        const float4 v1 = base[cell_off(c + ESTRIDE)];
        const float4 v2 = base[cell_off(c + 2 * ESTRIDE)];
        const float4 v3 = base[cell_off(c + 3 * ESTRIDE)];
        acc.x += (v0.x + v1.x) + (v2.x + v3.x);
        acc.y += (v0.y + v1.y) + (v2.y + v3.y);
        acc.z += (v0.z + v1.z) + (v2.z + v3.z);
        acc.w += (v0.w + v1.w) + (v2.w + v3.w);
    }
    for (; c < total; c += ESTRIDE) {
        const float4 v = base[cell_off(c)];
        acc.x += v.x; acc.y += v.y; acc.z += v.z; acc.w += v.w;
    }

    __shared__ float4 part[GROUPS][DQ_BB];   // 6 KB
    part[g][qd] = acc;
    __syncthreads();

    if (t < DQ_BB) {
        float4 sm = part[0][t];
#pragma unroll
        for (int p = 1; p < GROUPS; ++p) {
            const float4 v = part[p][t];
            sm.x += v.x; sm.y += v.y; sm.z += v.z; sm.w += v.w;
        }
        ((float4*)pooled)[((size_t)s * BT_TOTAL + bt) * DQ_BB + t] = sm;
    }
}

// ---------------- Kernel 2: GEMM (sums @ W)/count + b + LayerNorm + vis blend ----------------
// grid = BT_TOTAL/ROWS = 256, block = 512 = 128 col-quads x 4 K-partitions
__global__ __launch_bounds__(512) void gemm_ln_kernel(
    const float* __restrict__ pooled,    // [SPLIT,BT,384] raw partial sums
    const float* __restrict__ bboxes,    // [BT,4]
    const float* __restrict__ W,         // [384,512]
    const float* __restrict__ bias,      // [512]
    const float* __restrict__ gamma,     // [512]
    const float* __restrict__ beta,      // [512]
    const float* __restrict__ mask_tok,  // [512]
    const float* __restrict__ vis,       // [BT]
    float* __restrict__ out)             // [BT,512]
{
    const int tid  = threadIdx.x;
    const int part = tid >> 7;       // 0..3 (K partition)
    const int jq   = tid & 127;      // col quad 0..127
    const int r0   = blockIdx.x * ROWS;

    __shared__ float sp[ROWS][D_BB];            // 12 KB: the 8 summed rows
    __shared__ float red[KP - 1][32][CQ];       // 48 KB, element-major: conflict-free
    __shared__ float lnred[2][ROWS][2];
    __shared__ float s_invc[ROWS];

    // ---- stage pooled rows into LDS, summing the two split halves ----
    {
        const float4* pa = (const float4*)pooled + (size_t)r0 * DQ_BB;
        const float4* pb = (const float4*)pooled + ((size_t)BT_TOTAL + r0) * DQ_BB;
        float4* sp4 = (float4*)sp;
        for (int i = tid; i < ROWS * DQ_BB; i += 512) {
            const float4 a = pa[i];
            const float4 b = pb[i];
            sp4[i] = make_float4(a.x + b.x, a.y + b.y, a.z + b.z, a.w + b.w);
        }
    }
    if (tid < ROWS) {
        int x1, y1, wd, total;
        box_params(bboxes, r0 + tid, x1, y1, wd, total);
        s_invc[tid] = 1.f / (float)total;
    }
    __syncthreads();

    const float4* Wq = (const float4*)W;   // [384][128] float4
    float4 acc[ROWS];
#pragma unroll
    for (int r = 0; r < ROWS; ++r) acc[r] = make_float4(0.f, 0.f, 0.f, 0.f);

    const int dbase = part * KCHUNK;
#pragma unroll 2
    for (int i = 0; i < KCHUNK / 4; ++i) {
        const int d = dbase + i * 4;
        const float4 w0 = Wq[(size_t)(d + 0) * CQ + jq];
        const float4 w1 = Wq[(size_t)(d + 1) * CQ + jq];
        const float4 w2 = Wq[(size_t)(d + 2) * CQ + jq];
        const float4 w3 = Wq[(size_t)(d + 3) * CQ + jq];
#pragma unroll
        for (int r = 0; r < ROWS; ++r) {
            const float4 a = *(const float4*)&sp[r][d];   // LDS broadcast
            fma4(acc[r], a.x, w0);
            fma4(acc[r], a.y, w1);
            fma4(acc[r], a.z, w2);
            fma4(acc[r], a.w, w3);
        }
    }

    // ---- cross-partition reduction via LDS ----
    if (part != 0) {
#pragma unroll
        for (int r = 0; r < ROWS; ++r) {
            red[part - 1][r * 4 + 0][jq] = acc[r].x;
            red[part - 1][r * 4 + 1][jq] = acc[r].y;
            red[part - 1][r * 4 + 2][jq] = acc[r].z;
            red[part - 1][r * 4 + 3][jq] = acc[r].w;
        }
    }
    __syncthreads();

    if (part == 0) {
#pragma unroll
        for (int p = 0; p < KP - 1; ++p) {
#pragma unroll
            for (int r = 0; r < ROWS; ++r) {
                acc[r].x += red[p][r * 4 + 0][jq];
                acc[r].y += red[p][r * 4 + 1][jq];
                acc[r].z += red[p][r * 4 + 2][jq];
                acc[r].w += red[p][r * 4 + 3][jq];
            }
        }
        const float4 bj = ((const float4*)bias)[jq];
#pragma unroll
        for (int r = 0; r < ROWS; ++r) {
            const float ic = s_invc[r];
            acc[r].x = fmaf(acc[r].x, ic, bj.x);
            acc[r].y = fmaf(acc[r].y, ic, bj.y);
            acc[r].z = fmaf(acc[r].z, ic, bj.z);
            acc[r].w = fmaf(acc[r].w, ic, bj.w);
        }

        // ---- LN partial sums across 128 threads (2 waves) ----
        const int lane = tid & 63;
        const int wv   = tid >> 6;   // 0 or 1
#pragma unroll
        for (int r = 0; r < ROWS; ++r) {
            float s  = acc[r].x + acc[r].y + acc[r].z + acc[r].w;
            float s2 = acc[r].x * acc[r].x + acc[r].y * acc[r].y +
                       acc[r].z * acc[r].z + acc[r].w * acc[r].w;
#pragma unroll
            for (int off = 32; off >= 1; off >>= 1) {
                s  += __shfl_xor(s,  off);
                s2 += __shfl_xor(s2, off);
            }
            if (lane == 0) { lnred[wv][r][0] = s; lnred[wv][r][1] = s2; }
        }
    }
    __syncthreads();

    if (part == 0) {
        const float4 g4 = ((const float4*)gamma)[jq];
        const float4 b4 = ((const float4*)beta)[jq];
        const float4 m4 = ((const float4*)mask_tok)[jq];
#pragma unroll
        for (int r = 0; r < ROWS; ++r) {
            const float s    = lnred[0][r][0] + lnred[1][r][0];
            const float s2   = lnred[0][r][1] + lnred[1][r][1];
            const float mean = s * (1.f / (float)D_MODEL);
            const float var  = s2 * (1.f / (float)D_MODEL) - mean * mean;
            const float rstd = rsqrtf(var + LN_EPS);
            const float v    = vis[r0 + r];
            const float iv   = 1.f - v;
            float4 o;
            o.x = v * ((acc[r].x - mean) * rstd * g4.x + b4.x) + iv * m4.x;
            o.y = v * ((acc[r].y - mean) * rstd * g4.y + b4.y) + iv * m4.y;
            o.z = v * ((acc[r].z - mean) * rstd * g4.z + b4.z) + iv * m4.z;
            o.w = v * ((acc[r].w - mean) * rstd * g4.w + b4.w) + iv * m4.w;
            ((float4*)out)[(size_t)(r0 + r) * CQ + jq] = o;
        }
    }
}

extern "C" void kernel_launch(void* const* d_in, const int* in_sizes, int n_in,
                              void* d_out, int out_size, void* d_ws, size_t ws_size,
                              hipStream_t stream) {
    const float* patch  = (const float*)d_in[0];  // [2048,196,384]
    const float* bboxes = (const float*)d_in[1];  // [2048,4]
    const float* vis    = (const float*)d_in[2];  // [2048]
    // d_in[3] = B, d_in[4] = T (scalars, unused)
    const float* W      = (const float*)d_in[5];  // [384,512]
    const float* bias   = (const float*)d_in[6];  // [512]
    const float* gamma  = (const float*)d_in[7];  // [512]
    const float* beta   = (const float*)d_in[8];  // [512]
    const float* mtok   = (const float*)d_in[9];  // [1,512]

    float* pooled = (float*)d_ws;                 // [2,2048,384] partial sums, 6 MB
    float* out    = (float*)d_out;

    pool_kernel<<<BT_TOTAL * SPLIT, 384, 0, stream>>>(patch, bboxes, pooled);
    gemm_ln_kernel<<<BT_TOTAL / ROWS, 512, 0, stream>>>(
        pooled, bboxes, W, bias, gamma, beta, mtok, vis, out);
}